// Round 6
// baseline (3747.551 us; speedup 1.0000x reference)
//
#include <hip/hip_runtime.h>
#include <hip/hip_bf16.h>

using bf16 = __hip_bfloat16;
typedef short v8s __attribute__((ext_vector_type(8)));   // 8 bf16 = 4 VGPRs
typedef float v4f __attribute__((ext_vector_type(4)));   // MFMA C/D frag

__device__ __forceinline__ float sigmoidf_(float x) {
    return 1.0f / (1.0f + __expf(-x));
}
__device__ __forceinline__ float tanhf_(float x) {
    return 1.0f - 2.0f / (__expf(2.0f * x) + 1.0f);
}
__device__ __forceinline__ unsigned short bfbits(float f) {
    bf16 h = __float2bfloat16(f);
    return *reinterpret_cast<unsigned short*>(&h);
}
__device__ __forceinline__ float bf2f(unsigned short u) {
    bf16 h = *reinterpret_cast<bf16*>(&u);
    return __bfloat162float(h);
}
// sentinel: packed bf16 pair 0xFFFF,0xFFFF (-NaN). h = sigmoid*tanh is always
// finite in (-1,1); a real packed h u32 can never equal 0xFFFFFFFF.
__device__ __forceinline__ bool hasSent(unsigned long long v) {
    return ((unsigned)v == 0xFFFFFFFFu) || ((unsigned)(v >> 32) == 0xFFFFFFFFu);
}
// L1-bypassing load (reads this XCD's L2) — intra-XCD fast-path primitive.
__device__ __forceinline__ unsigned long long ld_sc0_u64(const unsigned long long* p) {
    unsigned long long r;
    asm volatile("global_load_dwordx2 %0, %1, off sc0\n\ts_waitcnt vmcnt(0)"
                 : "=v"(r) : "v"(p) : "memory");
    return r;
}
// Agent-scope (IC-authoritative) load — placement-agnostic progress guarantee.
__device__ __forceinline__ unsigned long long ld_agent_u64(const unsigned long long* p) {
    return __hip_atomic_load(p, __ATOMIC_RELAXED, __HIP_MEMORY_SCOPE_AGENT);
}
// L1-write-through store — lands in this XCD's L2.
__device__ __forceinline__ void st_sc0_u32(unsigned* p, unsigned v) {
    asm volatile("global_store_dword %0, %1, off sc0" :: "v"(p), "v"(v) : "memory");
}

// ---------------- fp32 -> bf16 converter ----------------
__global__ void f2b_kernel(const float* __restrict__ s, bf16* __restrict__ d, int n) {
    int idx = blockIdx.x * blockDim.x + threadIdx.x;
    int stride = gridDim.x * blockDim.x;
    for (int i = idx * 4; i < n; i += stride * 4) {
        float4 v = *reinterpret_cast<const float4*>(s + i);
        ushort4 u;
        u.x = bfbits(v.x); u.y = bfbits(v.y); u.z = bfbits(v.z); u.w = bfbits(v.w);
        *reinterpret_cast<ushort4*>(d + i) = u;
    }
}

// ---------------- sentinel fill for write-once h histories ----------------
__global__ void fill_sentinel(uint4* __restrict__ p, int n16) {
    int i = blockIdx.x * blockDim.x + threadIdx.x;
    int stride = gridDim.x * blockDim.x;
    uint4 v; v.x = v.y = v.z = v.w = 0xFFFFFFFFu;
    for (; i < n16; i += stride) p[i] = v;
}

// ---------------- init states (slot 0 of each history) ----------------
__global__ void init_state_kernel(const float* __restrict__ eh, const float* __restrict__ ec,
                                  float* __restrict__ hf, float* __restrict__ cf,
                                  bf16* __restrict__ h0h, bf16* __restrict__ h1h) {
    int idx = blockIdx.x * blockDim.x + threadIdx.x;
    if (idx >= 2 * 32 * 512) return;
    int l = idx >> 14;          // / 16384
    int rem = idx & 16383;
    hf[idx] = eh[idx];
    cf[idx] = ec[idx];
    bf16 hv = __float2bfloat16(eh[idx]);
    if (!l) h0h[rem] = hv;      // history slot 0 = initial state
    else    h1h[rem] = hv;
}

// ---------------- tail: final states -> d_out ----------------
__global__ void tail_kernel(const float* __restrict__ hf, const float* __restrict__ cf,
                            float* __restrict__ out) {
    int idx = blockIdx.x * blockDim.x + threadIdx.x;
    if (idx >= 2 * 32 * 512) return;
    out[1048576 + idx] = hf[idx];
    out[1048576 + 32768 + idx] = cf[idx];
}

// ---------------- bf16 MFMA GEMM: C[M,N] = A[M,K] @ W[N,K]^T (+bias) ----------------
__global__ __launch_bounds__(256) void gemm_bt(
    const bf16* __restrict__ A, const bf16* __restrict__ W,
    const float* __restrict__ bias,
    float* __restrict__ Cf, bf16* __restrict__ Cb,
    int M, int N, int K) {
    __shared__ __align__(16) bf16 As[64][72];
    __shared__ __align__(16) bf16 Bs[64][72];
    const int tid = threadIdx.x;
    const int wave = tid >> 6, lane = tid & 63;
    const int lr = lane & 15, lq = lane >> 4;
    const int m0 = blockIdx.y * 64, n0 = blockIdx.x * 64;

    v4f acc[4];
#pragma unroll
    for (int n = 0; n < 4; ++n) acc[n] = (v4f){0.f, 0.f, 0.f, 0.f};

    for (int k0 = 0; k0 < K; k0 += 64) {
        __syncthreads();
#pragma unroll
        for (int c = tid; c < 512; c += 256) {
            int row = c >> 3, c8 = (c & 7) * 8;
            *reinterpret_cast<v8s*>(&As[row][c8]) =
                *reinterpret_cast<const v8s*>(A + (size_t)(m0 + row) * K + k0 + c8);
            *reinterpret_cast<v8s*>(&Bs[row][c8]) =
                *reinterpret_cast<const v8s*>(W + (size_t)(n0 + row) * K + k0 + c8);
        }
        __syncthreads();
#pragma unroll
        for (int kk = 0; kk < 2; ++kk) {
            v8s a = *reinterpret_cast<const v8s*>(&As[wave * 16 + lr][kk * 32 + lq * 8]);
#pragma unroll
            for (int n = 0; n < 4; ++n) {
                v8s b = *reinterpret_cast<const v8s*>(&Bs[n * 16 + lr][kk * 32 + lq * 8]);
                acc[n] = __builtin_amdgcn_mfma_f32_16x16x32_bf16(a, b, acc[n], 0, 0, 0);
            }
        }
    }
#pragma unroll
    for (int n = 0; n < 4; ++n) {
        int col = n0 + n * 16 + lr;
        float bv = bias ? bias[col] : 0.0f;
#pragma unroll
        for (int r = 0; r < 4; ++r) {
            int row = m0 + wave * 16 + lq * 4 + r;
            float v = acc[n][r] + bv;
            if (Cf) Cf[(size_t)row * N + col] = v;
            if (Cb) Cb[(size_t)row * N + col] = __float2bfloat16(v);
        }
    }
}

// ---------------- persistent 2-layer LSTM, XCD-partitioned (static roles) ---
// Launch 256 WGs x 256 thr; 16KB dynamic-LDS pad forces 1 WG/CU => all 256
// WGs resident, one per CU. Documented dispatch heuristic: XCD = bid % 8.
// Static roles: bid%8==0 -> layer0 WG jj=bid/8 (expected all on XCD0);
// bid%8==1 -> layer1 (XCD1); all other 192 WGs EXIT IMMEDIATELY (no spins,
// no registration -> structurally deadlock-free).
//
// Placement-agnostic exchange (fixes R5's livelock):
//  - Producer DUAL-stores every h word: sc0 (write-through to local L2, the
//    intra-XCD fast path) + relaxed agent store (IC, the authoritative copy).
//  - Consumer detect: poll own first u64 with sc0 loads (L2-speed when
//    same-XCD), every 4th poll agent-scope (IC) so progress is guaranteed
//    even if placement is scrambled (cross-XCD L2 lines can be stale).
//  - After detect: bulk plain loads (fresh write-once addr -> L2 hit on fast
//    path), then sentinel-validate; straggler rounds alternate sc0 / agent.
//  - Layer1's h0-input (cross-XCD by design): plain prefetch at step start +
//    agent-reload validation (steady state: layer1 lags, data is IC-visible).
__global__ __launch_bounds__(256, 1) void lstm2_persist(
    int T, int t0,
    bf16* __restrict__ h0hist, bf16* __restrict__ h1hist, // write-once histories
    float* __restrict__ hf, float* __restrict__ cf,    // [2][32*512] fp32 state
    const bf16* __restrict__ Whh0,                     // [2048][512]
    const bf16* __restrict__ Wih1, const bf16* __restrict__ Whh1,
    const float* __restrict__ xpf,                     // layer0 fp32 xp [(b*T+t)*2048]
    const bf16* __restrict__ xpb,                      // layer0 bf16 xp (alt)
    const float* __restrict__ bih0, const float* __restrict__ bhh0,
    const float* __restrict__ bih1, const float* __restrict__ bhh1,
    float* __restrict__ outf, long out_stride_b)       // layer1 fp32 h seq (or null)
{
    extern __shared__ char dyn_pad[];                 // occupancy pad only
    __shared__ __align__(16) bf16 hs_h[32][520];      // own h(t-1); +8 pad
    __shared__ __align__(16) bf16 hs_x[32][520];      // layer1: h0(t)
    __shared__ float gs[4][32][16];
    __shared__ float bias_s[4][16];
    (void)dyn_pad;

    const int xcd = blockIdx.x & 7;
    if (xcd > 1) return;                              // 192 helper WGs exit
    const int layer = xcd;
    const int jj = blockIdx.x >> 3;                   // 0..31

    const int tid = threadIdx.x;
    const int wave = tid >> 6, lane = tid & 63;
    const int lr = lane & 15, lq = lane >> 4;
    const int hc0 = jj * 16;

    const float* bih_l = layer ? bih1 : bih0;
    const float* bhh_l = layer ? bhh1 : bhh0;
    if (tid < 64) {
        int g = tid >> 4, col = tid & 15;
        bias_s[g][col] = bih_l[g * 512 + hc0 + col] + bhh_l[g * 512 + hc0 + col];
    }

    // pointwise ownership: batch pb, cols pc & pc+1 (c register-resident)
    const int pb = tid >> 3;
    const int pc = (tid & 7) * 2;
    const int pgc = hc0 + pc;

    float* hf_l = hf + (size_t)layer * 16384;
    float* cf_l = cf + (size_t)layer * 16384;
    float c0, c1;
    {
        size_t sidx = (size_t)pb * 512 + pgc;
        c0 = cf_l[sidx]; c1 = cf_l[sidx + 1];
    }

    // Whh slice pinned in registers (64 VGPRs / thread).
    v8s breg_hh[16];
    {
        const bf16* Whh_l = layer ? Whh1 : Whh0;
        const bf16* wrow = Whh_l + (size_t)(wave * 512 + hc0 + lr) * 512 + lq * 8;
#pragma unroll
        for (int kk = 0; kk < 16; ++kk)
            breg_hh[kk] = *reinterpret_cast<const v8s*>(wrow + kk * 32);
    }
    // Layer1: Wih slice also in registers (64 more VGPRs; fine at 1 WG/CU).
    v8s breg_ih[16];
    if (layer) {
        const bf16* wrow = Wih1 + (size_t)(wave * 512 + hc0 + lr) * 512 + lq * 8;
#pragma unroll
        for (int kk = 0; kk < 16; ++kk)
            breg_ih[kk] = *reinterpret_cast<const v8s*>(wrow + kk * 32);
    }
    __syncthreads();

    // staging geometry: thread tid covers v8s at element tid*8 + i*2048,
    // LDS row (tid>>6)+4i, col (tid*8)&511; as u64s: index tid*2 + i*512 (+1)
    const int st_row = tid >> 6;
    const int st_col = (tid * 8) & 511;

    auto load_xp = [&](int t, float* xv) {
        if (xpf) {
            const float* xp = xpf + ((size_t)pb * T + t) * 2048;
            float2 a = *reinterpret_cast<const float2*>(xp + pgc);
            float2 b = *reinterpret_cast<const float2*>(xp + 512 + pgc);
            float2 c = *reinterpret_cast<const float2*>(xp + 1024 + pgc);
            float2 d = *reinterpret_cast<const float2*>(xp + 1536 + pgc);
            xv[0] = a.x; xv[1] = a.y; xv[2] = b.x; xv[3] = b.y;
            xv[4] = c.x; xv[5] = c.y; xv[6] = d.x; xv[7] = d.y;
        } else {
            const bf16* xp = xpb + ((size_t)pb * T + t) * 2048;
            unsigned a = *reinterpret_cast<const unsigned*>(xp + pgc);
            unsigned b = *reinterpret_cast<const unsigned*>(xp + 512 + pgc);
            unsigned c = *reinterpret_cast<const unsigned*>(xp + 1024 + pgc);
            unsigned d = *reinterpret_cast<const unsigned*>(xp + 1536 + pgc);
            xv[0] = bf2f(a & 0xffff); xv[1] = bf2f(a >> 16);
            xv[2] = bf2f(b & 0xffff); xv[3] = bf2f(b >> 16);
            xv[4] = bf2f(c & 0xffff); xv[5] = bf2f(c >> 16);
            xv[6] = bf2f(d & 0xffff); xv[7] = bf2f(d >> 16);
        }
    };

    float xcur[8];
    if (!layer) load_xp(0, xcur);

    bf16* own_base = layer ? h1hist : h0hist;

    for (int t = 0; t < T; ++t) {
        const bf16* own_src = own_base + (size_t)(t0 + t) * 16384;       // h(t-1)
        bf16* own_dst       = own_base + (size_t)(t0 + t + 1) * 16384;   // h(t)

        const unsigned long long* srcH =
            reinterpret_cast<const unsigned long long*>(own_src);
        const unsigned long long* srcX = layer
            ? reinterpret_cast<const unsigned long long*>(
                  h0hist + (size_t)(t0 + t + 1) * 16384)                 // h0(t)
            : nullptr;

        unsigned long long rh[16], rx[16];

        // ---- layer1: plain prefetch of h0(t) tile (cross-XCD; steady state
        //      it's long-produced and IC-visible; races fixed by agent reload) ----
        if (layer) {
#pragma unroll
            for (int i = 0; i < 8; ++i) {
                rx[2 * i]     = srcX[tid * 2 + i * 512];
                rx[2 * i + 1] = srcX[tid * 2 + i * 512 + 1];
            }
        }

        // ---- own-peer detect: sc0 poll (local L2); every 4th poll agent ----
        {
            unsigned long long h0w = ld_sc0_u64(srcH + tid * 2);
            unsigned pk = 0;
            while (hasSent(h0w)) {
                ++pk;
                h0w = (pk & 3u) ? ld_sc0_u64(srcH + tid * 2)
                                : ld_agent_u64(srcH + tid * 2);
            }
            rh[0] = h0w;
        }
        // fence: bulk loads must not hoist above the detect poll.
        asm volatile("" ::: "memory");

        // ---- bulk plain load of remaining 15 u64s (fast path: L2 hits) ----
        rh[1] = srcH[tid * 2 + 1];
#pragma unroll
        for (int i = 1; i < 8; ++i) {
            rh[2 * i]     = srcH[tid * 2 + i * 512];
            rh[2 * i + 1] = srcH[tid * 2 + i * 512 + 1];
        }

        // ---- validate own tile; straggler rounds alternate sc0 / agent ----
        for (unsigned round = 0;; ++round) {
            bool again = false;
#pragma unroll
            for (int k = 1; k < 16; ++k) {
                if (hasSent(rh[k])) {
                    const unsigned long long* p =
                        srcH + tid * 2 + (k >> 1) * 512 + (k & 1);
                    rh[k] = (round & 1u) ? ld_agent_u64(p) : ld_sc0_u64(p);
                    again = true;
                }
            }
            if (!again) break;
        }
        // ---- layer1: validate x tile; agent reload (authoritative, IC) ----
        if (layer) {
            for (;;) {
                bool again = false;
#pragma unroll
                for (int k = 0; k < 16; ++k) {
                    if (hasSent(rx[k])) {
                        rx[k] = ld_agent_u64(srcX + tid * 2 + (k >> 1) * 512 + (k & 1));
                        again = true;
                    }
                }
                if (!again) break;
            }
        }

        // ---- stage -> LDS ----
        if (layer) {
#pragma unroll
            for (int i = 0; i < 8; ++i) {
                union { unsigned long long u[2]; v8s v; } w;
                w.u[0] = rx[2 * i]; w.u[1] = rx[2 * i + 1];
                *reinterpret_cast<v8s*>(&hs_x[st_row + 4 * i][st_col]) = w.v;
            }
        }
#pragma unroll
        for (int i = 0; i < 8; ++i) {
            union { unsigned long long u[2]; v8s v; } w;
            w.u[0] = rh[2 * i]; w.u[1] = rh[2 * i + 1];
            *reinterpret_cast<v8s*>(&hs_h[st_row + 4 * i][st_col]) = w.v;
        }
        __syncthreads();

        // ---- gate GEMM from LDS; 4 independent MFMA chains for ILP ----
        v4f ax0 = (v4f){0.f, 0.f, 0.f, 0.f};
        v4f ax1 = (v4f){0.f, 0.f, 0.f, 0.f};
        v4f ah0 = (v4f){0.f, 0.f, 0.f, 0.f};
        v4f ah1 = (v4f){0.f, 0.f, 0.f, 0.f};
        if (layer) {
#pragma unroll
            for (int kk = 0; kk < 16; ++kk) {
                v8s a0x = *reinterpret_cast<const v8s*>(&hs_x[lr][lq * 8 + kk * 32]);
                v8s a1x = *reinterpret_cast<const v8s*>(&hs_x[16 + lr][lq * 8 + kk * 32]);
                ax0 = __builtin_amdgcn_mfma_f32_16x16x32_bf16(a0x, breg_ih[kk], ax0, 0, 0, 0);
                ax1 = __builtin_amdgcn_mfma_f32_16x16x32_bf16(a1x, breg_ih[kk], ax1, 0, 0, 0);
                v8s a0h = *reinterpret_cast<const v8s*>(&hs_h[lr][lq * 8 + kk * 32]);
                v8s a1h = *reinterpret_cast<const v8s*>(&hs_h[16 + lr][lq * 8 + kk * 32]);
                ah0 = __builtin_amdgcn_mfma_f32_16x16x32_bf16(a0h, breg_hh[kk], ah0, 0, 0, 0);
                ah1 = __builtin_amdgcn_mfma_f32_16x16x32_bf16(a1h, breg_hh[kk], ah1, 0, 0, 0);
            }
        } else {
#pragma unroll
            for (int kk = 0; kk < 16; kk += 2) {
                v8s a0e = *reinterpret_cast<const v8s*>(&hs_h[lr][lq * 8 + kk * 32]);
                v8s a1e = *reinterpret_cast<const v8s*>(&hs_h[16 + lr][lq * 8 + kk * 32]);
                ax0 = __builtin_amdgcn_mfma_f32_16x16x32_bf16(a0e, breg_hh[kk], ax0, 0, 0, 0);
                ax1 = __builtin_amdgcn_mfma_f32_16x16x32_bf16(a1e, breg_hh[kk], ax1, 0, 0, 0);
                v8s a0o = *reinterpret_cast<const v8s*>(&hs_h[lr][lq * 8 + (kk + 1) * 32]);
                v8s a1o = *reinterpret_cast<const v8s*>(&hs_h[16 + lr][lq * 8 + (kk + 1) * 32]);
                ah0 = __builtin_amdgcn_mfma_f32_16x16x32_bf16(a0o, breg_hh[kk + 1], ah0, 0, 0, 0);
                ah1 = __builtin_amdgcn_mfma_f32_16x16x32_bf16(a1o, breg_hh[kk + 1], ah1, 0, 0, 0);
            }
        }
        v4f acc0 = ax0 + ah0;
        v4f acc1 = ax1 + ah1;
#pragma unroll
        for (int r2 = 0; r2 < 4; ++r2) {
            gs[wave][lq * 4 + r2][lr]      = acc0[r2];
            gs[wave][16 + lq * 4 + r2][lr] = acc1[r2];
        }
        __syncthreads();

        // ---- pointwise: this thread's (pb, pc..pc+1) ----
        float xi0 = layer ? 0.f : xcur[0], xi1 = layer ? 0.f : xcur[1];
        float xf0 = layer ? 0.f : xcur[2], xf1 = layer ? 0.f : xcur[3];
        float xg0 = layer ? 0.f : xcur[4], xg1 = layer ? 0.f : xcur[5];
        float xo0 = layer ? 0.f : xcur[6], xo1 = layer ? 0.f : xcur[7];

        float gi0 = gs[0][pb][pc]     + xi0 + bias_s[0][pc];
        float gi1 = gs[0][pb][pc + 1] + xi1 + bias_s[0][pc + 1];
        float gf0 = gs[1][pb][pc]     + xf0 + bias_s[1][pc];
        float gf1 = gs[1][pb][pc + 1] + xf1 + bias_s[1][pc + 1];
        float gg0 = gs[2][pb][pc]     + xg0 + bias_s[2][pc];
        float gg1 = gs[2][pb][pc + 1] + xg1 + bias_s[2][pc + 1];
        float go0 = gs[3][pb][pc]     + xo0 + bias_s[3][pc];
        float go1 = gs[3][pb][pc + 1] + xo1 + bias_s[3][pc + 1];

        c0 = sigmoidf_(gf0) * c0 + sigmoidf_(gi0) * tanhf_(gg0);
        c1 = sigmoidf_(gf1) * c1 + sigmoidf_(gi1) * tanhf_(gg1);
        float h0v = sigmoidf_(go0) * tanhf_(c0);
        float h1v = sigmoidf_(go1) * tanhf_(c1);

        unsigned hp = (unsigned)bfbits(h0v) | ((unsigned)bfbits(h1v) << 16);
        unsigned* dstp = reinterpret_cast<unsigned*>(own_dst + (size_t)pb * 512 + pgc);
        st_sc0_u32(dstp, hp);                          // local L2 (fast path)
        __hip_atomic_store(dstp, hp, __ATOMIC_RELAXED, // IC (authoritative)
                           __HIP_MEMORY_SCOPE_AGENT);
        if (layer && outf) {
            float2 hv; hv.x = h0v; hv.y = h1v;
            *reinterpret_cast<float2*>(outf + (size_t)pb * out_stride_b + (size_t)t * 512 + pgc) = hv;
        }
        if (t == T - 1) {
            size_t sidx = (size_t)pb * 512 + pgc;
            hf_l[sidx] = h0v; hf_l[sidx + 1] = h1v;
            cf_l[sidx] = c0;  cf_l[sidx + 1] = c1;
        }

        // fence: keep the h stores from sinking below the next step's poll.
        asm volatile("" ::: "memory");
        // layer0: xp(t+1) prefetch; latency drains under next step's work.
        if (!layer && t + 1 < T) load_xp(t + 1, xcur);
    }
}

// ---------------- host orchestration ----------------
extern "C" void kernel_launch(void* const* d_in, const int* in_sizes, int n_in,
                              void* d_out, int out_size, void* d_ws, size_t ws_size,
                              hipStream_t stream) {
    constexpr int B = 32, S = 512, F = 64, I = 512, H = 512, G = 2048;

    const float* x    = (const float*)d_in[0];
    const float* fut  = (const float*)d_in[1];
    const float* eh   = (const float*)d_in[2];
    const float* ec   = (const float*)d_in[3];
    const float* fc_w = (const float*)d_in[4];
    const float* fc_b = (const float*)d_in[5];
    const float* ewih = (const float*)d_in[6];
    const float* ewhh = (const float*)d_in[7];
    const float* ebih = (const float*)d_in[8];
    const float* ebhh = (const float*)d_in[9];
    const float* dwih = (const float*)d_in[10];
    const float* dwhh = (const float*)d_in[11];
    const float* dbih = (const float*)d_in[12];
    const float* dbhh = (const float*)d_in[13];
    float* out = (float*)d_out;

    char* ws = (char*)d_ws;
    size_t off = 0;
    auto alloc = [&](size_t bytes) -> char* {
        char* p = ws + off;
        off += (bytes + 255) & ~(size_t)255;
        return p;
    };

    bf16* x_bf    = (bf16*)alloc((size_t)B * S * I * 2);
    bf16* fut_bf  = (bf16*)alloc((size_t)B * F * I * 2);
    bf16* fcw_bf  = (bf16*)alloc((size_t)H * I * 2);
    bf16* ewih_bf = (bf16*)alloc((size_t)2 * G * H * 2);
    bf16* ewhh_bf = (bf16*)alloc((size_t)2 * G * H * 2);
    bf16* dwih_bf = (bf16*)alloc((size_t)2 * G * H * 2);
    bf16* dwhh_bf = (bf16*)alloc((size_t)2 * G * H * 2);
    bf16* xt_bf   = (bf16*)alloc((size_t)B * S * H * 2);
    float* hf     = (float*)alloc((size_t)2 * B * H * 4);
    float* cf     = (float*)alloc((size_t)2 * B * H * 4);

    // write-once h histories: (S+F+1) slots x [B*H] bf16 each (contiguous pair)
    size_t histb = (size_t)(S + F + 1) * B * H * 2;
    bf16* h0hist = (bf16*)alloc(histb);
    bf16* h1hist = (bf16*)alloc(histb);

    size_t xp32_bytes = (size_t)B * S * G * 4;
    bool xp32 = ws_size >= off + xp32_bytes + 4096;
    float* Xf = nullptr; bf16* Xb = nullptr;
    if (xp32) Xf = (float*)alloc(xp32_bytes);
    else      Xb = (bf16*)alloc((size_t)B * S * G * 2);

    auto cvt = [&](const float* s, bf16* d, int n) {
        int blocks = (n / 4 + 255) / 256;
        if (blocks > 4096) blocks = 4096;
        f2b_kernel<<<blocks, 256, 0, stream>>>(s, d, n);
    };
    cvt(x, x_bf, B * S * I);
    cvt(fut, fut_bf, B * F * I);
    cvt(fc_w, fcw_bf, H * I);
    cvt(ewih, ewih_bf, 2 * G * H);
    cvt(ewhh, ewhh_bf, 2 * G * H);
    cvt(dwih, dwih_bf, 2 * G * H);
    cvt(dwhh, dwhh_bf, 2 * G * H);

    // sentinel-fill both histories (contiguous), THEN write slot-0 states.
    fill_sentinel<<<2048, 256, 0, stream>>>(
        reinterpret_cast<uint4*>(h0hist), (int)(2 * histb / 16));
    init_state_kernel<<<128, 256, 0, stream>>>(eh, ec, hf, cf, h0hist, h1hist);

    auto gemm = [&](const bf16* A, const bf16* W, const float* bias,
                    float* Cf_, bf16* Cb_, int M, int N, int K) {
        gemm_bt<<<dim3(N / 64, M / 64), 256, 0, stream>>>(A, W, bias, Cf_, Cb_, M, N, K);
    };

    // FC: xt = bf16(x @ fc_w^T + fc_b)
    gemm(x_bf, fcw_bf, fc_b, nullptr, xt_bf, B * S, H, I);

    // ---- Encoder: xp for layer 0 only, then XCD-partitioned persist ----
    // 256 WGs; 16KB dynamic-LDS pad forces 1 WG/CU (75KB static + 16KB > 80KB)
    // -> full CU cover; bid%8 picks the XCD under the round-robin heuristic.
    gemm(xt_bf, ewih_bf, nullptr, Xf, Xb, B * S, G, H);
    lstm2_persist<<<256, 256, 16384, stream>>>(
        S, /*t0=*/0,
        h0hist, h1hist,
        hf, cf,
        ewhh_bf,                              // Whh0
        ewih_bf + (size_t)G * H,              // Wih1
        ewhh_bf + (size_t)G * H,              // Whh1
        Xf, Xb,
        ebih, ebhh, ebih + G, ebhh + G,
        nullptr, 0);

    // ---- Decoder: starts at slot S (= encoder's final h, already in place) ----
    gemm(fut_bf, dwih_bf, nullptr, Xf, Xb, B * F, G, H);
    lstm2_persist<<<256, 256, 16384, stream>>>(
        F, /*t0=*/S,
        h0hist, h1hist,
        hf, cf,
        dwhh_bf,
        dwih_bf + (size_t)G * H,
        dwhh_bf + (size_t)G * H,
        Xf, Xb,
        dbih, dbhh, dbih + G, dbhh + G,
        out, (long)F * H);                    // dec_out [B,F,H] fp32

    // ---- Final decoder states ----
    tail_kernel<<<128, 256, 0, stream>>>(hf, cf, out);
}

// Round 7
// 2114.613 us; speedup vs baseline: 1.7722x; 1.7722x over previous
//
#include <hip/hip_runtime.h>
#include <hip/hip_bf16.h>

using bf16 = __hip_bfloat16;
typedef short v8s __attribute__((ext_vector_type(8)));   // 8 bf16 = 4 VGPRs
typedef float v4f __attribute__((ext_vector_type(4)));   // MFMA C/D frag

__device__ __forceinline__ float sigmoidf_(float x) {
    return 1.0f / (1.0f + __expf(-x));
}
__device__ __forceinline__ float tanhf_(float x) {
    return 1.0f - 2.0f / (__expf(2.0f * x) + 1.0f);
}
__device__ __forceinline__ unsigned short bfbits(float f) {
    bf16 h = __float2bfloat16(f);
    return *reinterpret_cast<unsigned short*>(&h);
}
__device__ __forceinline__ float bf2f(unsigned short u) {
    bf16 h = *reinterpret_cast<bf16*>(&u);
    return __bfloat162float(h);
}

// ---------------- fp32 -> bf16 converter ----------------
__global__ void f2b_kernel(const float* __restrict__ s, bf16* __restrict__ d, int n) {
    int idx = blockIdx.x * blockDim.x + threadIdx.x;
    int stride = gridDim.x * blockDim.x;
    for (int i = idx * 4; i < n; i += stride * 4) {
        float4 v = *reinterpret_cast<const float4*>(s + i);
        ushort4 u;
        u.x = bfbits(v.x); u.y = bfbits(v.y); u.z = bfbits(v.z); u.w = bfbits(v.w);
        *reinterpret_cast<ushort4*>(d + i) = u;
    }
}

// ---------------- init states (slot 0) + flag arrays ----------------
__global__ void init_state_kernel(const float* __restrict__ eh, const float* __restrict__ ec,
                                  float* __restrict__ hf, float* __restrict__ cf,
                                  bf16* __restrict__ h0h, bf16* __restrict__ h1h,
                                  unsigned* __restrict__ flags) {
    int idx = blockIdx.x * blockDim.x + threadIdx.x;
    if (idx < 128) flags[idx] = 0u;   // 2 phases x 64 WG flags
    if (idx >= 2 * 32 * 512) return;
    int l = idx >> 14;          // / 16384
    int rem = idx & 16383;
    hf[idx] = eh[idx];
    cf[idx] = ec[idx];
    bf16 hv = __float2bfloat16(eh[idx]);
    if (!l) h0h[rem] = hv;      // history slot 0 = initial state
    else    h1h[rem] = hv;
}

// ---------------- tail: final states -> d_out ----------------
__global__ void tail_kernel(const float* __restrict__ hf, const float* __restrict__ cf,
                            float* __restrict__ out) {
    int idx = blockIdx.x * blockDim.x + threadIdx.x;
    if (idx >= 2 * 32 * 512) return;
    out[1048576 + idx] = hf[idx];
    out[1048576 + 32768 + idx] = cf[idx];
}

// ---------------- bf16 MFMA GEMM: C[M,N] = A[M,K] @ W[N,K]^T (+bias) ----------------
__global__ __launch_bounds__(256) void gemm_bt(
    const bf16* __restrict__ A, const bf16* __restrict__ W,
    const float* __restrict__ bias,
    float* __restrict__ Cf, bf16* __restrict__ Cb,
    int M, int N, int K) {
    __shared__ __align__(16) bf16 As[64][72];
    __shared__ __align__(16) bf16 Bs[64][72];
    const int tid = threadIdx.x;
    const int wave = tid >> 6, lane = tid & 63;
    const int lr = lane & 15, lq = lane >> 4;
    const int m0 = blockIdx.y * 64, n0 = blockIdx.x * 64;

    v4f acc[4];
#pragma unroll
    for (int n = 0; n < 4; ++n) acc[n] = (v4f){0.f, 0.f, 0.f, 0.f};

    for (int k0 = 0; k0 < K; k0 += 64) {
        __syncthreads();
#pragma unroll
        for (int c = tid; c < 512; c += 256) {
            int row = c >> 3, c8 = (c & 7) * 8;
            *reinterpret_cast<v8s*>(&As[row][c8]) =
                *reinterpret_cast<const v8s*>(A + (size_t)(m0 + row) * K + k0 + c8);
            *reinterpret_cast<v8s*>(&Bs[row][c8]) =
                *reinterpret_cast<const v8s*>(W + (size_t)(n0 + row) * K + k0 + c8);
        }
        __syncthreads();
#pragma unroll
        for (int kk = 0; kk < 2; ++kk) {
            v8s a = *reinterpret_cast<const v8s*>(&As[wave * 16 + lr][kk * 32 + lq * 8]);
#pragma unroll
            for (int n = 0; n < 4; ++n) {
                v8s b = *reinterpret_cast<const v8s*>(&Bs[n * 16 + lr][kk * 32 + lq * 8]);
                acc[n] = __builtin_amdgcn_mfma_f32_16x16x32_bf16(a, b, acc[n], 0, 0, 0);
            }
        }
    }
#pragma unroll
    for (int n = 0; n < 4; ++n) {
        int col = n0 + n * 16 + lr;
        float bv = bias ? bias[col] : 0.0f;
#pragma unroll
        for (int r = 0; r < 4; ++r) {
            int row = m0 + wave * 16 + lq * 4 + r;
            float v = acc[n][r] + bv;
            if (Cf) Cf[(size_t)row * N + col] = v;
            if (Cb) Cb[(size_t)row * N + col] = __float2bfloat16(v);
        }
    }
}

// ---------------- persistent 2-layer pipelined LSTM stack ----------------
// 64 WGs x 256 thr, co-resident. WGs 0..31: layer 0 (WG j owns hidden cols
// [j*16,j*16+16), wave w = gate w). WGs 32..63: layer 1.
//
// R1's proven protocol (drain -> flag -> poll -> cached load), with the one
// change of LAYER-DECOUPLED polling:
//  - h goes to write-once history slots (slot j holds h(j-1); slot t0 =
//    initial state). Write-once => layer0 may run arbitrarily far ahead of
//    layer1 with no WAR hazard.
//  - Producer: __syncthreads() (drains vmcnt(0): h stores agent-visible)
//    then tid0 posts flag = t+1 (agent scope). Flags CERTIFY data.
//  - Consumer layer0 at step t: poll ONLY layer0 flags >= t (never waits on
//    the heavier layer1), then plain cached loads of h(t-1) (fresh write-once
//    lines -> one IC fetch shared by the 8 WGs per XCD via L2).
//  - Consumer layer1 at step t: poll layer0 flags >= t+1 FIRST (pre-satisfied
//    once layer0 runs ahead), issue h0(t) cached loads, THEN poll own peers
//    >= t (h0 fetch latency hides under this wait), then load own h1(t-1).
__global__ __launch_bounds__(256, 1) void lstm2_persist(
    int T, int t0,
    bf16* __restrict__ h0hist, bf16* __restrict__ h1hist, // write-once histories
    float* __restrict__ hf, float* __restrict__ cf,    // [2][32*512] fp32 state
    const bf16* __restrict__ Whh0,                     // [2048][512]
    const bf16* __restrict__ Wih1, const bf16* __restrict__ Whh1,
    const float* __restrict__ xpf,                     // layer0 fp32 xp [(b*T+t)*2048]
    const bf16* __restrict__ xpb,                      // layer0 bf16 xp (alt)
    const float* __restrict__ bih0, const float* __restrict__ bhh0,
    const float* __restrict__ bih1, const float* __restrict__ bhh1,
    float* __restrict__ outf, long out_stride_b,       // layer1 fp32 h seq (or null)
    unsigned* __restrict__ flags)                      // 64 per-WG step counters
{
    __shared__ __align__(16) bf16 hs_h[32][520];      // own h(t-1); +8 pad
    __shared__ __align__(16) bf16 hs_x[32][520];      // layer1: h0(t)
    __shared__ float gs[4][32][16];
    __shared__ float bias_s[4][16];

    const int tid = threadIdx.x;
    const int layer = blockIdx.x >> 5;
    const int jj = blockIdx.x & 31;
    const int wave = tid >> 6, lane = tid & 63;
    const int lr = lane & 15, lq = lane >> 4;
    const int hc0 = jj * 16;

    const float* bih_l = layer ? bih1 : bih0;
    const float* bhh_l = layer ? bhh1 : bhh0;
    if (tid < 64) {
        int g = tid >> 4, col = tid & 15;
        bias_s[g][col] = bih_l[g * 512 + hc0 + col] + bhh_l[g * 512 + hc0 + col];
    }

    // pointwise ownership: batch pb, cols pc & pc+1 (c register-resident)
    const int pb = tid >> 3;
    const int pc = (tid & 7) * 2;
    const int pgc = hc0 + pc;

    float* hf_l = hf + (size_t)layer * 16384;
    float* cf_l = cf + (size_t)layer * 16384;
    float c0, c1;
    {
        size_t sidx = (size_t)pb * 512 + pgc;
        c0 = cf_l[sidx]; c1 = cf_l[sidx + 1];
    }

    // Whh slice pinned in registers (64 VGPRs / thread).
    v8s breg_hh[16];
    {
        const bf16* Whh_l = layer ? Whh1 : Whh0;
        const bf16* wrow = Whh_l + (size_t)(wave * 512 + hc0 + lr) * 512 + lq * 8;
#pragma unroll
        for (int kk = 0; kk < 16; ++kk)
            breg_hh[kk] = *reinterpret_cast<const v8s*>(wrow + kk * 32);
    }
    // Layer1: Wih slice also in registers (64 more VGPRs; fine at 1 WG/CU).
    v8s breg_ih[16];
    if (layer) {
        const bf16* wrow = Wih1 + (size_t)(wave * 512 + hc0 + lr) * 512 + lq * 8;
#pragma unroll
        for (int kk = 0; kk < 16; ++kk)
            breg_ih[kk] = *reinterpret_cast<const v8s*>(wrow + kk * 32);
    }
    __syncthreads();

    // staging geometry: thread tid covers v8s at element tid*8 + i*2048,
    // LDS row (tid>>6)+4i, col (tid*8)&511
    const int st_row = tid >> 6;
    const int st_col = (tid * 8) & 511;

    auto load_xp = [&](int t, float* xv) {
        if (xpf) {
            const float* xp = xpf + ((size_t)pb * T + t) * 2048;
            float2 a = *reinterpret_cast<const float2*>(xp + pgc);
            float2 b = *reinterpret_cast<const float2*>(xp + 512 + pgc);
            float2 c = *reinterpret_cast<const float2*>(xp + 1024 + pgc);
            float2 d = *reinterpret_cast<const float2*>(xp + 1536 + pgc);
            xv[0] = a.x; xv[1] = a.y; xv[2] = b.x; xv[3] = b.y;
            xv[4] = c.x; xv[5] = c.y; xv[6] = d.x; xv[7] = d.y;
        } else {
            const bf16* xp = xpb + ((size_t)pb * T + t) * 2048;
            unsigned a = *reinterpret_cast<const unsigned*>(xp + pgc);
            unsigned b = *reinterpret_cast<const unsigned*>(xp + 512 + pgc);
            unsigned c = *reinterpret_cast<const unsigned*>(xp + 1024 + pgc);
            unsigned d = *reinterpret_cast<const unsigned*>(xp + 1536 + pgc);
            xv[0] = bf2f(a & 0xffff); xv[1] = bf2f(a >> 16);
            xv[2] = bf2f(b & 0xffff); xv[3] = bf2f(b >> 16);
            xv[4] = bf2f(c & 0xffff); xv[5] = bf2f(c >> 16);
            xv[6] = bf2f(d & 0xffff); xv[7] = bf2f(d >> 16);
        }
    };

    float xcur[8];
    if (!layer) load_xp(0, xcur);

    bf16* own_base = layer ? h1hist : h0hist;

    for (int t = 0; t < T; ++t) {
        const bf16* own_src = own_base + (size_t)(t0 + t) * 16384;       // h(t-1)
        bf16* own_dst       = own_base + (size_t)(t0 + t + 1) * 16384;   // h(t)

        v8s rh[8], rx[8];

        if (layer) {
            // ---- poll layer0 flags >= t+1 (usually pre-satisfied) ----
            if (tid < 64) {
                for (;;) {
                    unsigned v = __hip_atomic_load(&flags[tid & 31],
                                     __ATOMIC_RELAXED, __HIP_MEMORY_SCOPE_AGENT);
                    if (__all(v >= (unsigned)(t + 1))) break;
                }
            }
            __syncthreads();
            // ---- issue h0(t) cached loads; latency hides under peer poll ----
            const v8s* sx = reinterpret_cast<const v8s*>(
                h0hist + (size_t)(t0 + t + 1) * 16384);
#pragma unroll
            for (int i = 0; i < 8; ++i) rx[i] = sx[tid + i * 256];
            // ---- poll own peers >= t ----
            if (tid < 64) {
                for (;;) {
                    unsigned v = __hip_atomic_load(&flags[32 + (tid & 31)],
                                     __ATOMIC_RELAXED, __HIP_MEMORY_SCOPE_AGENT);
                    if (__all(v >= (unsigned)t)) break;
                }
            }
            __syncthreads();
        } else {
            // ---- layer0: poll ONLY layer0 flags >= t ----
            if (tid < 64) {
                for (;;) {
                    unsigned v = __hip_atomic_load(&flags[tid & 31],
                                     __ATOMIC_RELAXED, __HIP_MEMORY_SCOPE_AGENT);
                    if (__all(v >= (unsigned)t)) break;
                }
            }
            __syncthreads();
        }

        // ---- cached load of own h(t-1) (write-once lines, flag-certified) ----
        {
            const v8s* sh = reinterpret_cast<const v8s*>(own_src);
#pragma unroll
            for (int i = 0; i < 8; ++i) rh[i] = sh[tid + i * 256];
        }

        // ---- stage -> LDS ----
        if (layer) {
#pragma unroll
            for (int i = 0; i < 8; ++i)
                *reinterpret_cast<v8s*>(&hs_x[st_row + 4 * i][st_col]) = rx[i];
        }
#pragma unroll
        for (int i = 0; i < 8; ++i)
            *reinterpret_cast<v8s*>(&hs_h[st_row + 4 * i][st_col]) = rh[i];
        __syncthreads();

        // ---- gate GEMM from LDS; 4 independent MFMA chains for ILP ----
        v4f ax0 = (v4f){0.f, 0.f, 0.f, 0.f};
        v4f ax1 = (v4f){0.f, 0.f, 0.f, 0.f};
        v4f ah0 = (v4f){0.f, 0.f, 0.f, 0.f};
        v4f ah1 = (v4f){0.f, 0.f, 0.f, 0.f};
        if (layer) {
#pragma unroll
            for (int kk = 0; kk < 16; ++kk) {
                v8s a0x = *reinterpret_cast<const v8s*>(&hs_x[lr][lq * 8 + kk * 32]);
                v8s a1x = *reinterpret_cast<const v8s*>(&hs_x[16 + lr][lq * 8 + kk * 32]);
                ax0 = __builtin_amdgcn_mfma_f32_16x16x32_bf16(a0x, breg_ih[kk], ax0, 0, 0, 0);
                ax1 = __builtin_amdgcn_mfma_f32_16x16x32_bf16(a1x, breg_ih[kk], ax1, 0, 0, 0);
                v8s a0h = *reinterpret_cast<const v8s*>(&hs_h[lr][lq * 8 + kk * 32]);
                v8s a1h = *reinterpret_cast<const v8s*>(&hs_h[16 + lr][lq * 8 + kk * 32]);
                ah0 = __builtin_amdgcn_mfma_f32_16x16x32_bf16(a0h, breg_hh[kk], ah0, 0, 0, 0);
                ah1 = __builtin_amdgcn_mfma_f32_16x16x32_bf16(a1h, breg_hh[kk], ah1, 0, 0, 0);
            }
        } else {
#pragma unroll
            for (int kk = 0; kk < 16; kk += 2) {
                v8s a0e = *reinterpret_cast<const v8s*>(&hs_h[lr][lq * 8 + kk * 32]);
                v8s a1e = *reinterpret_cast<const v8s*>(&hs_h[16 + lr][lq * 8 + kk * 32]);
                ax0 = __builtin_amdgcn_mfma_f32_16x16x32_bf16(a0e, breg_hh[kk], ax0, 0, 0, 0);
                ax1 = __builtin_amdgcn_mfma_f32_16x16x32_bf16(a1e, breg_hh[kk], ax1, 0, 0, 0);
                v8s a0o = *reinterpret_cast<const v8s*>(&hs_h[lr][lq * 8 + (kk + 1) * 32]);
                v8s a1o = *reinterpret_cast<const v8s*>(&hs_h[16 + lr][lq * 8 + (kk + 1) * 32]);
                ah0 = __builtin_amdgcn_mfma_f32_16x16x32_bf16(a0o, breg_hh[kk + 1], ah0, 0, 0, 0);
                ah1 = __builtin_amdgcn_mfma_f32_16x16x32_bf16(a1o, breg_hh[kk + 1], ah1, 0, 0, 0);
            }
        }
        v4f acc0 = ax0 + ah0;
        v4f acc1 = ax1 + ah1;
#pragma unroll
        for (int r2 = 0; r2 < 4; ++r2) {
            gs[wave][lq * 4 + r2][lr]      = acc0[r2];
            gs[wave][16 + lq * 4 + r2][lr] = acc1[r2];
        }
        __syncthreads();

        // ---- pointwise: this thread's (pb, pc..pc+1) ----
        float xi0 = layer ? 0.f : xcur[0], xi1 = layer ? 0.f : xcur[1];
        float xf0 = layer ? 0.f : xcur[2], xf1 = layer ? 0.f : xcur[3];
        float xg0 = layer ? 0.f : xcur[4], xg1 = layer ? 0.f : xcur[5];
        float xo0 = layer ? 0.f : xcur[6], xo1 = layer ? 0.f : xcur[7];

        float gi0 = gs[0][pb][pc]     + xi0 + bias_s[0][pc];
        float gi1 = gs[0][pb][pc + 1] + xi1 + bias_s[0][pc + 1];
        float gf0 = gs[1][pb][pc]     + xf0 + bias_s[1][pc];
        float gf1 = gs[1][pb][pc + 1] + xf1 + bias_s[1][pc + 1];
        float gg0 = gs[2][pb][pc]     + xg0 + bias_s[2][pc];
        float gg1 = gs[2][pb][pc + 1] + xg1 + bias_s[2][pc + 1];
        float go0 = gs[3][pb][pc]     + xo0 + bias_s[3][pc];
        float go1 = gs[3][pb][pc + 1] + xo1 + bias_s[3][pc + 1];

        c0 = sigmoidf_(gf0) * c0 + sigmoidf_(gi0) * tanhf_(gg0);
        c1 = sigmoidf_(gf1) * c1 + sigmoidf_(gi1) * tanhf_(gg1);
        float h0v = sigmoidf_(go0) * tanhf_(c0);
        float h1v = sigmoidf_(go1) * tanhf_(c1);

        unsigned hp = (unsigned)bfbits(h0v) | ((unsigned)bfbits(h1v) << 16);
        __hip_atomic_store(reinterpret_cast<unsigned*>(own_dst + (size_t)pb * 512 + pgc),
                           hp, __ATOMIC_RELAXED, __HIP_MEMORY_SCOPE_AGENT);
        if (layer && outf) {
            float2 hv; hv.x = h0v; hv.y = h1v;
            *reinterpret_cast<float2*>(outf + (size_t)pb * out_stride_b + (size_t)t * 512 + pgc) = hv;
        }
        if (t == T - 1) {
            size_t sidx = (size_t)pb * 512 + pgc;
            hf_l[sidx] = h0v; hf_l[sidx + 1] = h1v;
            cf_l[sidx] = c0;  cf_l[sidx + 1] = c1;
        }

        // ---- drain + flag post (R1's proven certify step) ----
        __syncthreads();   // vmcnt(0): h stores agent-visible before flag
        if (tid == 0)
            __hip_atomic_store(&flags[blockIdx.x], (unsigned)(t + 1),
                               __ATOMIC_RELAXED, __HIP_MEMORY_SCOPE_AGENT);
        // layer0: xp(t+1) prefetch; its HBM latency drains during the next
        // step's poll window, off the flag-store critical path.
        if (!layer && t + 1 < T) load_xp(t + 1, xcur);
    }
}

// ---------------- host orchestration ----------------
extern "C" void kernel_launch(void* const* d_in, const int* in_sizes, int n_in,
                              void* d_out, int out_size, void* d_ws, size_t ws_size,
                              hipStream_t stream) {
    constexpr int B = 32, S = 512, F = 64, I = 512, H = 512, G = 2048;

    const float* x    = (const float*)d_in[0];
    const float* fut  = (const float*)d_in[1];
    const float* eh   = (const float*)d_in[2];
    const float* ec   = (const float*)d_in[3];
    const float* fc_w = (const float*)d_in[4];
    const float* fc_b = (const float*)d_in[5];
    const float* ewih = (const float*)d_in[6];
    const float* ewhh = (const float*)d_in[7];
    const float* ebih = (const float*)d_in[8];
    const float* ebhh = (const float*)d_in[9];
    const float* dwih = (const float*)d_in[10];
    const float* dwhh = (const float*)d_in[11];
    const float* dbih = (const float*)d_in[12];
    const float* dbhh = (const float*)d_in[13];
    float* out = (float*)d_out;

    char* ws = (char*)d_ws;
    size_t off = 0;
    auto alloc = [&](size_t bytes) -> char* {
        char* p = ws + off;
        off += (bytes + 255) & ~(size_t)255;
        return p;
    };

    bf16* x_bf    = (bf16*)alloc((size_t)B * S * I * 2);
    bf16* fut_bf  = (bf16*)alloc((size_t)B * F * I * 2);
    bf16* fcw_bf  = (bf16*)alloc((size_t)H * I * 2);
    bf16* ewih_bf = (bf16*)alloc((size_t)2 * G * H * 2);
    bf16* ewhh_bf = (bf16*)alloc((size_t)2 * G * H * 2);
    bf16* dwih_bf = (bf16*)alloc((size_t)2 * G * H * 2);
    bf16* dwhh_bf = (bf16*)alloc((size_t)2 * G * H * 2);
    bf16* xt_bf   = (bf16*)alloc((size_t)B * S * H * 2);
    float* hf     = (float*)alloc((size_t)2 * B * H * 4);
    float* cf     = (float*)alloc((size_t)2 * B * H * 4);
    unsigned* flags = (unsigned*)alloc(128 * sizeof(unsigned)); // 2 phases x 64

    // write-once h histories: (S+F+1) slots x [B*H] bf16 each
    size_t histb = (size_t)(S + F + 1) * B * H * 2;
    bf16* h0hist = (bf16*)alloc(histb);
    bf16* h1hist = (bf16*)alloc(histb);

    size_t xp32_bytes = (size_t)B * S * G * 4;
    bool xp32 = ws_size >= off + xp32_bytes + 4096;
    float* Xf = nullptr; bf16* Xb = nullptr;
    if (xp32) Xf = (float*)alloc(xp32_bytes);
    else      Xb = (bf16*)alloc((size_t)B * S * G * 2);

    auto cvt = [&](const float* s, bf16* d, int n) {
        int blocks = (n / 4 + 255) / 256;
        if (blocks > 4096) blocks = 4096;
        f2b_kernel<<<blocks, 256, 0, stream>>>(s, d, n);
    };
    cvt(x, x_bf, B * S * I);
    cvt(fut, fut_bf, B * F * I);
    cvt(fc_w, fcw_bf, H * I);
    cvt(ewih, ewih_bf, 2 * G * H);
    cvt(ewhh, ewhh_bf, 2 * G * H);
    cvt(dwih, dwih_bf, 2 * G * H);
    cvt(dwhh, dwhh_bf, 2 * G * H);

    init_state_kernel<<<128, 256, 0, stream>>>(eh, ec, hf, cf, h0hist, h1hist, flags);

    auto gemm = [&](const bf16* A, const bf16* W, const float* bias,
                    float* Cf_, bf16* Cb_, int M, int N, int K) {
        gemm_bt<<<dim3(N / 64, M / 64), 256, 0, stream>>>(A, W, bias, Cf_, Cb_, M, N, K);
    };

    // FC: xt = bf16(x @ fc_w^T + fc_b)
    gemm(x_bf, fcw_bf, fc_b, nullptr, xt_bf, B * S, H, I);

    // ---- Encoder: xp for layer 0 only, then decoupled 2-layer persist ----
    gemm(xt_bf, ewih_bf, nullptr, Xf, Xb, B * S, G, H);
    lstm2_persist<<<64, 256, 0, stream>>>(
        S, /*t0=*/0,
        h0hist, h1hist,
        hf, cf,
        ewhh_bf,                              // Whh0
        ewih_bf + (size_t)G * H,              // Wih1
        ewhh_bf + (size_t)G * H,              // Whh1
        Xf, Xb,
        ebih, ebhh, ebih + G, ebhh + G,
        nullptr, 0,
        flags + 0);

    // ---- Decoder: starts at slot S (= encoder's final h, already in place) ----
    gemm(fut_bf, dwih_bf, nullptr, Xf, Xb, B * F, G, H);
    lstm2_persist<<<64, 256, 0, stream>>>(
        F, /*t0=*/S,
        h0hist, h1hist,
        hf, cf,
        dwhh_bf,
        dwih_bf + (size_t)G * H,
        dwhh_bf + (size_t)G * H,
        Xf, Xb,
        dbih, dbhh, dbih + G, dbhh + G,
        out, (long)F * H,                     // dec_out [B,F,H] fp32
        flags + 64);

    // ---- Final decoder states ----
    tail_kernel<<<128, 256, 0, stream>>>(hf, cf, out);
}